// Round 1
// baseline (94.196 us; speedup 1.0000x reference)
//
#include <hip/hip_runtime.h>
#include <hip/hip_bf16.h>
#include <hip/hip_fp16.h>

typedef _Float16 f16;
typedef __attribute__((ext_vector_type(4))) _Float16 f16x4;
typedef __attribute__((ext_vector_type(8))) _Float16 f16x8;
typedef __attribute__((ext_vector_type(4))) float f32x4;

#define DIM     2048
#define BROWS   8192
#define NCOLS   1221      // 111 nodes * 11
#define NPAD    1280      // padded to 10 tiles of 128
#define NNODES  111
#define BM      128
#define BN      128
#define BK      32

// ---------- prep: Bt[c][d] = W[c/11][d][c%11] (fp16, zero-padded cols) ----------
__global__ void prep_b(const float* __restrict__ W, f16* __restrict__ Bt) {
    int idx = blockIdx.x * 256 + threadIdx.x;   // 1280 blocks: c = idx>>8, 256 d-groups of 8
    int c  = idx >> 8;
    int d0 = (idx & 255) * 8;
    f16x8 v;
    if (c < NCOLS) {
        int n = c / 11, k = c - n * 11;
        const float* src = W + (size_t)n * DIM * 11 + k;
        #pragma unroll
        for (int e = 0; e < 8; ++e) v[e] = (f16)src[(size_t)(d0 + e) * 11];
    } else {
        #pragma unroll
        for (int e = 0; e < 8; ++e) v[e] = (f16)0.f;
    }
    *(f16x8*)(Bt + (size_t)c * DIM + d0) = v;
}

// ---------- GEMM: L[b][c] = sum_d x[b,d] * Bt[c,d]  (m97 128x128 structure) ----------
__global__ __launch_bounds__(256, 2) void gemm_f16(const float* __restrict__ X,
                                                   const f16* __restrict__ Bt,
                                                   float* __restrict__ L) {
    __shared__ f16 As[BM * BK];   // [128][32] fp16, 8 KB
    __shared__ f16 Bs[BN * BK];   // [128][32] fp16, 8 KB

    int bid = blockIdx.x;                 // 640 = 8 XCDs * 80
    int swz = (bid & 7) * 80 + (bid >> 3);
    int mt = swz / 10, nt = swz - mt * 10;
    int m0 = mt * BM, n0 = nt * BN;

    int t = threadIdx.x;
    int w = t >> 6, l = t & 63;
    int r = l & 15, q = l >> 4;
    int wm = w >> 1, wn = w & 1;

    f32x4 acc[4][4];
    #pragma unroll
    for (int i = 0; i < 4; ++i)
        #pragma unroll
        for (int j = 0; j < 4; ++j) acc[i][j] = (f32x4)0.f;

    // A staging map: round p: row = p*32 + (t>>3), col = (t&7)*4  (float4 loads)
    int a_row = t >> 3;
    int a_col = (t & 7) * 4;
    const float* xbase = X + (size_t)(m0 + a_row) * DIM + a_col;
    // B staging map: round p: row = p*64 + w*16 + (l>>2), off = (l&3)*8 f16 (16B)
    int b_row = w * 16 + (l >> 2);
    int b_off = (l & 3) * 8;
    const f16* btbase = Bt + (size_t)(n0 + b_row) * DIM + b_off;
    f16* bs_base = Bs + w * 512;          // wave-uniform LDS base (lane*16B added by HW)

    for (int kt = 0; kt < DIM / BK; ++kt) {
        __syncthreads();
        // ---- stage B via async global->LDS, 2 rounds x 16B/lane ----
        #pragma unroll
        for (int p = 0; p < 2; ++p) {
            __builtin_amdgcn_global_load_lds(
                (const __attribute__((address_space(1))) void*)(btbase + (size_t)p * 64 * DIM + kt * BK),
                (__attribute__((address_space(3))) void*)(bs_base + p * 2048),
                16, 0, 0);
        }
        // ---- stage A: f32 global -> cvt fp16 -> LDS ----
        #pragma unroll
        for (int p = 0; p < 4; ++p) {
            f32x4 v = *(const f32x4*)(xbase + (size_t)p * 32 * DIM + kt * BK);
            f16x4 h; h[0] = (f16)v[0]; h[1] = (f16)v[1]; h[2] = (f16)v[2]; h[3] = (f16)v[3];
            *(f16x4*)(As + (a_row + p * 32) * BK + a_col) = h;
        }
        __syncthreads();
        // ---- fragments + MFMA ----
        f16x8 af[4], bf[4];
        #pragma unroll
        for (int m = 0; m < 4; ++m) af[m] = *(const f16x8*)(As + (wm * 64 + m * 16 + r) * BK + q * 8);
        #pragma unroll
        for (int n = 0; n < 4; ++n) bf[n] = *(const f16x8*)(Bs + (wn * 64 + n * 16 + r) * BK + q * 8);
        #pragma unroll
        for (int m = 0; m < 4; ++m)
            #pragma unroll
            for (int n = 0; n < 4; ++n)
                acc[m][n] = __builtin_amdgcn_mfma_f32_16x16x32_f16(af[m], bf[n], acc[m][n], 0, 0, 0);
    }

    // ---- write logits: C/D map col=lane&15, row=(lane>>4)*4+j (m89-verified) ----
    #pragma unroll
    for (int m = 0; m < 4; ++m) {
        int row = m0 + wm * 64 + m * 16 + q * 4;
        #pragma unroll
        for (int n = 0; n < 4; ++n) {
            int col = n0 + wn * 64 + n * 16 + r;
            #pragma unroll
            for (int j = 0; j < 4; ++j)
                L[(size_t)(row + j) * NPAD + col] = acc[m][n][j];
        }
    }
}

// ---------- epilogue: softmax per node (k=11) + 3-level product tree ----------
__global__ void tree_epi(const float* __restrict__ L, const float* __restrict__ bias,
                         float* __restrict__ out) {
    __shared__ float P[4][NNODES * 11];   // 4 rows/block, 4884B each
    int w = threadIdx.x >> 6, l = threadIdx.x & 63;
    int row = blockIdx.x * 4 + w;
    const float* Lr = L + (size_t)row * NPAD;

    for (int n = l; n < NNODES; n += 64) {
        float v[11], mx = -1e30f;
        #pragma unroll
        for (int k = 0; k < 11; ++k) { v[k] = Lr[n * 11 + k] + bias[n * 11 + k]; mx = fmaxf(mx, v[k]); }
        float s = 0.f;
        #pragma unroll
        for (int k = 0; k < 11; ++k) { v[k] = __expf(v[k] - mx); s += v[k]; }
        float inv = 1.f / s;
        #pragma unroll
        for (int k = 0; k < 11; ++k) P[w][n * 11 + k] = v[k] * inv;
    }
    __syncthreads();
    const float* Pw = P[w];
    for (int c = l; c < 1000; c += 64) {
        int i  = c / 100;
        int j  = (c % 100) / 10;
        int mm = c % 10;
        float p = Pw[1 + i] * Pw[(1 + i) * 11 + 1 + j] * Pw[(11 + 10 * i + j) * 11 + 1 + mm];
        out[(size_t)row * 1000 + c] = p;
    }
    if (row == 0 && threadIdx.x == 0) out[(size_t)BROWS * 1000] = 0.f;  // penalty
}

extern "C" void kernel_launch(void* const* d_in, const int* in_sizes, int n_in,
                              void* d_out, int out_size, void* d_ws, size_t ws_size,
                              hipStream_t stream) {
    const float* x    = (const float*)d_in[0];
    // d_in[1] = labels (unused by reference computation)
    const float* W    = (const float*)d_in[2];
    const float* bias = (const float*)d_in[3];
    float* out = (float*)d_out;

    // ws layout: Bt fp16 [1280][2048] = 5,242,880 B ; L f32 [8192][1280] = 41,943,040 B
    f16*   Bt = (f16*)d_ws;
    float* L  = (float*)((char*)d_ws + (size_t)NPAD * DIM * sizeof(f16));

    prep_b  <<<NPAD, 256, 0, stream>>>(W, Bt);
    gemm_f16<<<(BROWS / BM) * (NPAD / BN), 256, 0, stream>>>(x, Bt, L);
    tree_epi<<<BROWS / 4, 256, 0, stream>>>(L, bias, out);
}